// Round 10
// baseline (112.616 us; speedup 1.0000x reference)
//
#include <hip/hip_runtime.h>
#include <cmath>

#define WAVE 64
#define TPB  256
#define FTPB 1024
#define JPB  128    // broadcast extent per block -> C = M/JPB partials
#define MMAX 4096

__device__ __forceinline__ float fastrcp(float x) { return __builtin_amdgcn_rcpf(x); }

__device__ __forceinline__ unsigned sortable_u32(float f) {
    unsigned b = __float_as_uint(f);
    return (b & 0x80000000u) ? ~b : (b | 0x80000000u);
}

// mask may arrive as u8 bool, i32, or f32 — probe byte pattern.
__device__ __forceinline__ int mask_mode(const void* maskp) {
    const unsigned char* mb = (const unsigned char*)maskp;
    unsigned char b0 = mb[0], b1 = mb[1];
    if (b0 != 0 && b1 != 0) return 0;   // u8
    if (b0 != 0) return 1;              // i32
    return 2;                           // f32
}
__device__ __forceinline__ float mask_v(const void* maskp, int t, int mode) {
    if (mode == 0) return ((const unsigned char*)maskp)[t] ? 1.0f : 0.0f;
    if (mode == 1) return ((const int*)maskp)[t] ? 1.0f : 0.0f;
    return (((const float*)maskp)[t] != 0.0f) ? 1.0f : 0.0f;
}
__device__ __forceinline__ int midx(int m, int nsh, int N) {
    return (nsh >= 0) ? (m >> nsh) : (m / N);
}

// ---------------- prep: pack per-box records (32B) -------------------------
//   pk[2m]   = {x1, y1, x2, y2}
//   pk[2m+1] = {area, v, bias, 0}   bias = v>0 ? 0 : -inf
__global__ __launch_bounds__(TPB) void prep_kernel(
        const float4* __restrict__ pred, const float4* __restrict__ tgt,
        const void* __restrict__ maskp, int M, int nsh, int N,
        float4* __restrict__ pkS, float4* __restrict__ pkT) {
    int m = blockIdx.x * blockDim.x + threadIdx.x;
    if (m >= M) return;
    float vm  = mask_v(maskp, midx(m, nsh, N), mask_mode(maskp));
    float bias = (vm > 0.0f) ? 0.0f : -INFINITY;

    float4 p = pred[m];
    float x1 = p.x - 0.5f * p.z, y1 = p.y - 0.5f * p.w;
    float x2 = p.x + 0.5f * p.z, y2 = p.y + 0.5f * p.w;
    pkS[2 * m]     = make_float4(x1, y1, x2, y2);
    pkS[2 * m + 1] = make_float4((x2 - x1) * (y2 - y1), vm, bias, 0.0f);

    float4 t = tgt[m];
    pkT[2 * m]     = t;
    pkT[2 * m + 1] = make_float4((t.z - t.x) * (t.w - t.y), vm, bias, 0.0f);
}

// ---------------------------------------------------------------------------
// Pass: two lane-local roles split by blockIdx. Branchless inner loop:
// broadcast side via blockIdx-uniform scalar loads (pipelines freely),
// mask folded in as +bias (argmax) / *v (colsum). h = giou+1 form.
// ---------------------------------------------------------------------------
__global__ __launch_bounds__(TPB) void pass_kernel(
        const float4* __restrict__ pkS, const float4* __restrict__ pkT,
        int M, int RB,
        unsigned long long* __restrict__ keypart, float* __restrict__ colpart) {
    const int C   = M / JPB;                    // macro-chunks
    const int tid = threadIdx.x;

    if ((int)blockIdx.x < RB) {
        // rows-role: 256 lane-resident tgt rows x JPB broadcast pred cols
        const int rb = blockIdx.x / C;
        const int cc = blockIdx.x % C;          // uniform chunk
        const int r  = rb * TPB + tid;
        float4 a  = pkT[2 * r];
        float  aA = pkT[2 * r + 1].x;
        const float4* __restrict__ bp = pkS + (size_t)cc * (2 * JPB);  // block-uniform

        float best = -INFINITY;
        int   bidx = 0;
#pragma unroll 8
        for (int j = 0; j < JPB; ++j) {
            float4 b  = bp[2 * j];              // scalar broadcast load
            float4 bm = bp[2 * j + 1];          // {aB, v, bias, _}
            float ltx = fmaxf(a.x, b.x), lty = fmaxf(a.y, b.y);
            float rbx = fminf(a.z, b.z), rby = fminf(a.w, b.w);
            float w = fmaxf(rbx - ltx, 0.0f), h = fmaxf(rby - lty, 0.0f);
            float inter = w * h;
            float uni = aA + bm.x - inter;
            float cx1 = fminf(a.x, b.x), cy1 = fminf(a.y, b.y);
            float cx2 = fmaxf(a.z, b.z), cy2 = fmaxf(a.w, b.w);
            float areaC = (cx2 - cx1) * (cy2 - cy1);   // >= 0 by construction
            float hval = fmaf(uni, fastrcp(areaC), inter * fastrcp(uni));
            float val  = hval + bm.z;           // masked col -> -inf
            if (val > best) { best = val; bidx = cc * JPB + j; } // strict >, asc j
        }
        keypart[(size_t)cc * M + r] = ((unsigned long long)sortable_u32(best) << 32)
                                    | (unsigned)(~bidx);
    } else {
        // cols-role: 256 lane-resident pred cols x JPB broadcast tgt rows
        const int b2 = blockIdx.x - RB;
        const int cb = b2 / C;
        const int rc = b2 % C;                  // uniform chunk
        const int c  = cb * TPB + tid;
        float4 b  = pkS[2 * c];
        float  aB = pkS[2 * c + 1].x;
        const float4* __restrict__ ap = pkT + (size_t)rc * (2 * JPB);  // block-uniform

        float csum = 0.0f;
#pragma unroll 8
        for (int j = 0; j < JPB; ++j) {
            float4 a  = ap[2 * j];              // scalar broadcast load
            float4 am = ap[2 * j + 1];          // {aA, v, bias, _}
            float ltx = fmaxf(a.x, b.x), lty = fmaxf(a.y, b.y);
            float rbx = fminf(a.z, b.z), rby = fminf(a.w, b.w);
            float w = fmaxf(rbx - ltx, 0.0f), h = fmaxf(rby - lty, 0.0f);
            float inter = w * h;
            float uni = am.x + aB - inter;
            float cx1 = fminf(a.x, b.x), cy1 = fminf(a.y, b.y);
            float cx2 = fmaxf(a.z, b.z), cy2 = fmaxf(a.w, b.w);
            float areaC = (cx2 - cx1) * (cy2 - cy1);
            float hval = fmaf(uni, fastrcp(areaC), inter * fastrcp(uni));
            csum = fmaf(am.y, hval, csum);      // * v (0 or 1)
        }
        colpart[(size_t)rc * M + c] = csum;
    }
}

// ---------------------------------------------------------------------------
// redfin: ONE block, 1024 threads. Phase A combines the C partials per
// element with 8-wide BATCHED independent loads (16+ outstanding per wave —
// this is what rounds 7/8 got wrong with a latency-chained serial loop).
// Results parked in LDS. Phase B: f64 scalar reductions + output.
// ---------------------------------------------------------------------------
__device__ __forceinline__ double wave_sum_d(double x) {
    for (int off = 32; off >= 1; off >>= 1) x += __shfl_xor(x, off);
    return x;
}
__device__ __forceinline__ unsigned long long umax8(
        unsigned long long k0, unsigned long long k1, unsigned long long k2,
        unsigned long long k3, unsigned long long k4, unsigned long long k5,
        unsigned long long k6, unsigned long long k7) {
    unsigned long long a = (k0 > k1) ? k0 : k1;
    unsigned long long b = (k2 > k3) ? k2 : k3;
    unsigned long long c = (k4 > k5) ? k4 : k5;
    unsigned long long d = (k6 > k7) ? k6 : k7;
    a = (a > b) ? a : b; c = (c > d) ? c : d;
    return (a > c) ? a : c;
}

__global__ __launch_bounds__(FTPB) void redfin_kernel(
        const float4* __restrict__ pkS, const float4* __restrict__ pkT,
        const unsigned long long* __restrict__ keypart,
        const float* __restrict__ colpart, int M, int C,
        float* __restrict__ out) {
    __shared__ float cs_lds[MMAX];
    __shared__ int   idx_lds[MMAX];
    __shared__ double red[4 * (FTPB / WAVE)];
    const int tid = threadIdx.x;

    // phase A: combine C partials per element, batched 8-wide (C % 8 == 0)
    for (int m = tid; m < M; m += FTPB) {
        unsigned long long kmax = 0;            // all real keys > 0
        float s = 0.0f;
        for (int cc = 0; cc < C; cc += 8) {
            const unsigned long long* kp = keypart + (size_t)cc * M + m;
            const float* sp = colpart + (size_t)cc * M + m;
            unsigned long long k0 = kp[0 * (size_t)M], k1 = kp[1 * (size_t)M];
            unsigned long long k2 = kp[2 * (size_t)M], k3 = kp[3 * (size_t)M];
            unsigned long long k4 = kp[4 * (size_t)M], k5 = kp[5 * (size_t)M];
            unsigned long long k6 = kp[6 * (size_t)M], k7 = kp[7 * (size_t)M];
            float s0 = sp[0 * (size_t)M], s1 = sp[1 * (size_t)M];
            float s2 = sp[2 * (size_t)M], s3 = sp[3 * (size_t)M];
            float s4 = sp[4 * (size_t)M], s5 = sp[5 * (size_t)M];
            float s6 = sp[6 * (size_t)M], s7 = sp[7 * (size_t)M];
            unsigned long long kb = umax8(k0, k1, k2, k3, k4, k5, k6, k7);
            kmax = (kb > kmax) ? kb : kmax;
            s += ((s0 + s1) + (s2 + s3)) + ((s4 + s5) + (s6 + s7));
        }
        idx_lds[m] = (int)(~(unsigned)kmax);
        cs_lds[m] = s;
    }
    __syncthreads();

    // phase B: f64 scalar reductions
    double sumV = 0.0, S2 = 0.0, S1h = 0.0, bbox = 0.0;
    for (int m = tid; m < M; m += FTPB) {
        float4 tm = pkT[2 * m];
        float  vi = pkT[2 * m + 1].y;
        int    k  = idx_lds[m];
        float4 sk = pkS[2 * k];
        float  vk = pkS[2 * k + 1].y;
        sumV += (double)vi;
        S2   += (double)vk;
        S1h  += (double)vk * (double)cs_lds[k];
        bbox += (double)vi * (double)(fabsf(sk.x - tm.x) + fabsf(sk.y - tm.y) +
                                      fabsf(sk.z - tm.z) + fabsf(sk.w - tm.w));
    }
    sumV = wave_sum_d(sumV);
    S2   = wave_sum_d(S2);
    S1h  = wave_sum_d(S1h);
    bbox = wave_sum_d(bbox);
    int wid = tid >> 6, lane = tid & (WAVE - 1);
    const int NW = FTPB / WAVE;
    if (lane == 0) {
        red[wid] = sumV; red[NW + wid] = S2; red[2 * NW + wid] = S1h; red[3 * NW + wid] = bbox;
    }
    __syncthreads();
    if (tid == 0) {
        double a = 0, b = 0, c = 0, d = 0;
        for (int w = 0; w < NW; ++w) {
            a += red[w]; b += red[NW + w]; c += red[2 * NW + w]; d += red[3 * NW + w];
        }
        // colsum_g = colsum_h - sumV  =>  loss_giou = 2 - S1h/(sumV*S2)
        out[0] = (float)(2.0 - c / (a * b));
        out[1] = (float)(d / (4.0 * a));
    }
}

// ---------------------------------------------------------------------------
extern "C" void kernel_launch(void* const* d_in, const int* in_sizes, int n_in,
                              void* d_out, int out_size, void* d_ws, size_t ws_size,
                              hipStream_t stream) {
    const float4* pred = (const float4*)d_in[0];
    const float4* tgt  = (const float4*)d_in[1];
    const void*   mask = d_in[2];

    int M = in_sizes[0] / 4;        // 4096 (B*T*N); multiple of 256
    int N = M / in_sizes[2];        // boxes per mask entry (8)
    int nsh = -1;
    for (int s = 0; s < 31; ++s) if ((1 << s) == N) { nsh = s; break; }

    int C = M / JPB;                // 32

    char* ws = (char*)d_ws;
    float4* pkS = (float4*)ws;                             ws += (size_t)M * 32;
    float4* pkT = (float4*)ws;                             ws += (size_t)M * 32;
    unsigned long long* keypart = (unsigned long long*)ws; ws += (size_t)C * M * 8;
    float* colpart = (float*)ws;                           ws += (size_t)C * M * 4;
    float* out = (float*)d_out;

    prep_kernel<<<(M + TPB - 1) / TPB, TPB, 0, stream>>>(
        pred, tgt, mask, M, nsh, N, pkS, pkT);

    int RB = (M / TPB) * C;         // 512 rows-role blocks
    pass_kernel<<<2 * RB, TPB, 0, stream>>>(pkS, pkT, M, RB, keypart, colpart);

    redfin_kernel<<<1, FTPB, 0, stream>>>(pkS, pkT, keypart, colpart, M, C, out);
}